// Round 16
// baseline (333.558 us; speedup 1.0000x reference)
//
#include <hip/hip_runtime.h>
#include <hip/hip_bf16.h>
#include <stdint.h>

typedef __bf16 bf16_t;
typedef __bf16 bf16x8 __attribute__((ext_vector_type(8)));
typedef short short8 __attribute__((ext_vector_type(8)));
typedef float f32x4 __attribute__((ext_vector_type(4)));
typedef float f32x16 __attribute__((ext_vector_type(16)));

#define RS512  0.044194173824159216f   // 1/sqrt(512)
#define RS4608 0.014731391274719739f   // 1/sqrt(512*9)

// ---------------- K1: style vector  s[b][c] = (w[b,:] . lw[c,:])/sqrt(512) + lb[c]
__global__ void k_style(const float* __restrict__ w, const float* __restrict__ lw,
                        const float* __restrict__ lb, float* __restrict__ s) {
  int b = blockIdx.y;
  int c = blockIdx.x * 256 + threadIdx.x;
  const float4* wr = (const float4*)(w + b * 512);
  const float4* lr = (const float4*)(lw + (size_t)c * 512);
  float acc = 0.f;
#pragma unroll 4
  for (int d = 0; d < 128; ++d) {
    float4 a = wr[d], q = lr[d];
    acc += a.x * q.x + a.y * q.y + a.z * q.z + a.w * q.w;
  }
  s[b * 512 + c] = acc * RS512 + lb[c];
}

// ---------------- K2: wsq + bf16 W fragments for 32x32x16 MFMA (r13-verified); zeros zbuf
// 1KB block per (tap, c=i>>5, fo=o>>5, ks=(i>>4)&1); lane = (o&31)+32*((i>>3)&1), elem=i&7
__global__ void k_wprep(const float* __restrict__ cw, float* __restrict__ wsq,
                        bf16_t* __restrict__ bwf, f32x4* __restrict__ zb) {
  if (blockIdx.x == 0) zb[threadIdx.x] = (f32x4)0.f;  // 256*16B = 4KB zeros
  int idx = blockIdx.x * 256 + threadIdx.x;  // o*512 + i
  int o = idx >> 9, i = idx & 511;
  float v[9];
  float ss = 0.f;
#pragma unroll
  for (int t = 0; t < 9; ++t) {
    float x = cw[(size_t)idx * 9 + t] * RS4608;
    v[t] = x;
    ss += x * x;
  }
  wsq[idx] = ss;
  int c32 = i >> 5, fo = o >> 5, ks = (i >> 4) & 1;
  int ln = (o & 31) + ((i >> 3) & 1) * 32;
#pragma unroll
  for (int t = 0; t < 9; ++t) {
    size_t e = ((size_t)(((t * 16 + c32) * 16 + fo) * 2 + ks) << 9) + ln * 8 + (i & 7);
    bwf[e] = (bf16_t)v[t];
  }
}

// ---------------- K3: sigma_inv[b][o] = rsqrt( sum_i s[b,i]^2 * wsq[o,i] + eps )
__global__ void k_sigma(const float* __restrict__ s, const float* __restrict__ wsq,
                        float* __restrict__ sinv) {
  __shared__ float s2[512];
  int b = blockIdx.y;
  int o = blockIdx.x * 256 + threadIdx.x;
  for (int i = threadIdx.x; i < 512; i += 256) {
    float v = s[b * 512 + i];
    s2[i] = v * v;
  }
  __syncthreads();
  const float4* qr = (const float4*)(wsq + (size_t)o * 512);
  float acc = 0.f;
#pragma unroll 4
  for (int d = 0; d < 128; ++d) {
    float4 q = qr[d];
    acc += q.x * s2[4 * d] + q.y * s2[4 * d + 1] + q.z * s2[4 * d + 2] + q.w * s2[4 * d + 3];
  }
  sinv[b * 512 + o] = rsqrtf(acc + 1e-8f);
}

// ---------------- K4: xt[b][h][cc][kgr][col][8ch] = bf16(x*s); coalesced (r13-verified)
__global__ void k_xt(const float* __restrict__ x, const float* __restrict__ s,
                     bf16_t* __restrict__ xt) {
  int ic = blockIdx.x, h = blockIdx.y, b = blockIdx.z;
  __shared__ __align__(16) bf16_t tile[8192];  // [16 grp][64 col][8ch]
  int t = threadIdx.x;
  int wcol = t & 63;
  int g = t >> 6;
#pragma unroll
  for (int blk = 0; blk < 4; ++blk) {
    int grp = blk * 4 + g;
    bf16x8 vec;
#pragma unroll
    for (int k = 0; k < 8; ++k) {
      int i = ic * 128 + grp * 8 + k;
      float v = x[(((size_t)b * 512 + i) * 64 + h) * 64 + wcol] * s[b * 512 + i];
      vec[k] = (bf16_t)v;
    }
    *(bf16x8*)((char*)tile + grp * 1024 + wcol * 16) = vec;
  }
  __syncthreads();
  char* dst = (char*)xt + ((((size_t)b * 64 + h) * 16 + ic * 4) << 12) + g * 1024 + wcol * 16;
#pragma unroll
  for (int j = 0; j < 4; ++j) {
    bf16x8 v = *(bf16x8*)((char*)tile + (j * 4 + g) * 1024 + wcol * 16);
    *(bf16x8*)(dst + j * 4096) = v;
  }
}

// ---------------- K5: implicit-GEMM conv; r11 staging skeleton + 32x32x16 MFMA
#define AS1 __attribute__((address_space(1)))
#define AS3 __attribute__((address_space(3)))

__device__ __forceinline__ void gl16(const void* g, void* l) {
  __builtin_amdgcn_global_load_lds((const AS1 void*)g, (AS3 void*)l, 16, 0, 0);
}

#define VMCNT(n) asm volatile("s_waitcnt vmcnt(" #n ")" ::: "memory")
#define BAR __builtin_amdgcn_s_barrier()

// ws layout: zbuf@0 (4KB zeros), xt@4096, bwf@67112960
#define XT0 4096u

// LDS: W[3 slabs][8192B] @0..24575 ; X[2 bufs][6 rows][4 kgr][64 col][16B] @24576..73727
//      + 1KB tail guard (masked edge reads may touch up to 73744)
__global__ __launch_bounds__(512, 4) void k_conv(
    const char* __restrict__ wsb, const bf16_t* __restrict__ bwf,
    const float* __restrict__ sinv, const float* __restrict__ noise,
    const float* __restrict__ snz, const float* __restrict__ bias,
    float* __restrict__ out) {
  __shared__ __align__(16) char lds[74752];

  const int t = threadIdx.x;
  const int rq = blockIdx.x;        // output rows h0..h0+3
  const int OY = blockIdx.y;        // o0 = OY*128
  const int b = blockIdx.z;
  const int h0 = rq * 4;
  const int lane = t & 63;
  const int wv = t >> 6;            // 8 waves
  const int wm = wv & 1;            // o-offset wm*64
  const int wn = wv >> 1;           // output row h0+wn

  f32x16 acc[2][2] = {};            // [f(o-32-blk)][nf(pos-32-blk)]

  // ---- X staging: 24 slots of 1KB per buffer; wave wv owns slots wv*3..+2
  uint32_t xsoff[3], xdst[3], xsel[3];
#pragma unroll
  for (int k = 0; k < 3; ++k) {
    int slot = wv * 3 + k, row = slot >> 2, q = slot & 3;
    int gr = h0 - 1 + row;
    int valid = ((unsigned)gr < 64u) ? 1 : 0;
    uint32_t so = valid ? (XT0 + (uint32_t)b * 4194304u + (uint32_t)gr * 65536u +
                           (uint32_t)q * 1024u)
                        : 0u;  // zbuf
    xsoff[k] = __builtin_amdgcn_readfirstlane(so);
    xdst[k] = __builtin_amdgcn_readfirstlane((uint32_t)(24576 + row * 4096 + q * 1024));
    xsel[k] = __builtin_amdgcn_readfirstlane((uint32_t)valid);
  }

  auto stX = [&](int k, uint32_t cxoff, int xb) {
    uint32_t co = xsel[k] ? cxoff : 0u;  // halo slots always read zbuf
    gl16(wsb + xsoff[k] + co + (size_t)(lane * 16), lds + xdst[k] + (uint32_t)(xb * 24576));
  };

  // ---- W staging into LDS (r11 pattern): 1KB/wave per 8KB tap slab
  const char* wgsrc = (const char*)bwf + OY * 8192 + wv * 1024 + lane * 16;
  auto stW = [&](uint32_t srcoff, int slab) {
    gl16(wgsrc + srcoff, lds + slab * 8192 + (wv << 10));
  };

  // ---- LDS read bases
  const uint32_t woff = (uint32_t)((wm * 2) * 2048 + (lane << 4));  // + f*2048 + ks*1024
  const uint32_t pXbase =
      (uint32_t)(24576 + wn * 4096 + (lane >> 5) * 1024 + (lane & 31) * 16);
  const bool cl = (lane & 31) == 0;
  const bool cr = (lane & 31) == 31;

// one tap: 4 A ds_reads + 4 B ds_reads + 8 MFMA(32x32x16)
#define CTAP(J, XB)                                                            \
  {                                                                            \
    const int ky = (J) / 3, kx = (J) % 3;                                      \
    bf16x8 af[4];                                                              \
    _Pragma("unroll") for (int f = 0; f < 2; ++f)                              \
        _Pragma("unroll") for (int ks = 0; ks < 2; ++ks)                       \
            af[f * 2 + ks] = *(const bf16x8*)(                                 \
                lds + (uint32_t)(((J) % 3) * 8192) + woff +                    \
                (uint32_t)(f * 2048 + ks * 1024));                             \
    __builtin_amdgcn_s_setprio(1);                                             \
    _Pragma("unroll") for (int nf = 0; nf < 2; ++nf) {                         \
      bf16x8 b0, b1;                                                           \
      {                                                                        \
        short8 xv = *(const short8*)(lds + pXbase +                            \
            (uint32_t)((XB) * 24576 + ky * 4096 + nf * 512 + (kx - 1) * 16));  \
        if (kx == 0 && nf == 0) xv = cl ? (short8)0 : xv;                      \
        if (kx == 2 && nf == 1) xv = cr ? (short8)0 : xv;                      \
        b0 = __builtin_bit_cast(bf16x8, xv);                                   \
      }                                                                        \
      {                                                                        \
        short8 xv = *(const short8*)(lds + pXbase +                            \
            (uint32_t)((XB) * 24576 + ky * 4096 + 2048 + nf * 512 +            \
                       (kx - 1) * 16));                                        \
        if (kx == 0 && nf == 0) xv = cl ? (short8)0 : xv;                      \
        if (kx == 2 && nf == 1) xv = cr ? (short8)0 : xv;                      \
        b1 = __builtin_bit_cast(bf16x8, xv);                                   \
      }                                                                        \
      _Pragma("unroll") for (int f = 0; f < 2; ++f) {                          \
        acc[f][nf] = __builtin_amdgcn_mfma_f32_32x32x16_bf16(                  \
            af[f * 2 + 0], b0, acc[f][nf], 0, 0, 0);                           \
        acc[f][nf] = __builtin_amdgcn_mfma_f32_32x32x16_bf16(                  \
            af[f * 2 + 1], b1, acc[f][nf], 0, 0, 0);                           \
      }                                                                        \
    }                                                                          \
    __builtin_amdgcn_s_setprio(0);                                             \
  }

// phase (r11 verbatim issue pattern + ledger):
//   steady {3,4,5,4,3,2,2,2,2} ; last chunk {2,2,2,2,2,2,2,1,0}
#define PHASE(CWB, CXB, JC, LAST, XB)                                          \
  {                                                                            \
    if ((JC) + 2 <= 8) stW((CWB) + (uint32_t)((JC) + 2) * 524288u, ((JC) + 2) % 3); \
    else if (!(LAST)) stW((CWB) + 32768u + (uint32_t)((JC) - 7) * 524288u, ((JC) + 2) % 3); \
    if (!(LAST) && (JC) < 3) stX((JC), (CXB), (XB) ^ 1);                       \
    if (LAST) {                                                                \
      if ((JC) <= 6) { VMCNT(2); }                                             \
      else if ((JC) == 7) { VMCNT(1); }                                        \
      else { VMCNT(0); }                                                       \
    } else {                                                                   \
      if ((JC) == 0 || (JC) == 4) { VMCNT(3); }                                \
      else if ((JC) == 1 || (JC) == 3) { VMCNT(4); }                           \
      else if ((JC) == 2) { VMCNT(5); }                                        \
      else { VMCNT(2); }                                                       \
    }                                                                          \
    __builtin_amdgcn_s_barrier();                                              \
    CTAP((JC), (XB));                                                          \
  }

  // prologue: X[0] (halo slots read zbuf) + W taps 0,1 -> slabs 0,1
#pragma unroll
  for (int k = 0; k < 3; ++k) stX(k, 0u, 0);
  stW(0u, 0);
  stW(524288u, 1);
  VMCNT(0); BAR;

  uint32_t cwb = 0, cxb = 4096;
#pragma unroll 1
  for (int ci = 0; ci < 7; ++ci) {
#pragma unroll
    for (int jc = 0; jc < 9; ++jc) PHASE(cwb, cxb, jc, 0, 0);
    cwb += 32768u; cxb += 4096u;
#pragma unroll
    for (int jc = 0; jc < 9; ++jc) PHASE(cwb, cxb, jc, 0, 1);
    cwb += 32768u; cxb += 4096u;
  }
#pragma unroll
  for (int jc = 0; jc < 9; ++jc) PHASE(cwb, cxb, jc, 0, 0);  // chunk 14 (stages X[15])
  cwb += 32768u;
#pragma unroll
  for (int jc = 0; jc < 9; ++jc) PHASE(cwb, 0u, jc, 1, 1);   // chunk 15 (LAST)

  // epilogue: demod + noise + bias + leaky relu
  // 32x32 C/D mapping (verified m74/m101/r13): col=lane&31, row=(r&3)+8*(r>>2)+4*(lane>>5)
  const float* sb = sinv + b * 512;
  const int colb = lane & 31;
  const int rq4 = (lane >> 5) * 4;
  const int prow = h0 + wn;
  float nz0 = noise[(size_t)b * 4096 + prow * 64 + colb];
  float nz1 = noise[(size_t)b * 4096 + prow * 64 + 32 + colb];
#pragma unroll
  for (int f = 0; f < 2; ++f) {
#pragma unroll
    for (int r = 0; r < 16; ++r) {
      int o = OY * 128 + wm * 64 + f * 32 + (r & 3) + 8 * (r >> 2) + rq4;
      float sv = sb[o];
      float nw = snz[o];
      float bv = bias[o];
      float* orow = out + (((size_t)b * 512 + o) * 64 + prow) * 64;
      float v0 = acc[f][0][r] * sv + nw * nz0 + bv;
      float v1 = acc[f][1][r] * sv + nw * nz1 + bv;
      orow[colb] = v0 > 0.f ? v0 : 0.2f * v0;
      orow[32 + colb] = v1 > 0.f ? v1 : 0.2f * v1;
    }
  }
}

extern "C" void kernel_launch(void* const* d_in, const int* in_sizes, int n_in,
                              void* d_out, int out_size, void* d_ws, size_t ws_size,
                              hipStream_t stream) {
  const float* x     = (const float*)d_in[0];
  const float* w     = (const float*)d_in[1];
  const float* noise = (const float*)d_in[2];
  const float* lw    = (const float*)d_in[3];
  const float* lb    = (const float*)d_in[4];
  const float* cw    = (const float*)d_in[5];
  const float* snz   = (const float*)d_in[6];
  const float* bias  = (const float*)d_in[7];
  float* out = (float*)d_out;

  char* ws = (char*)d_ws;
  char*   zbuf = ws;                            //      4,096 B zeros
  bf16_t* xt   = (bf16_t*)(ws + 4096);          // 67,108,864 B : [b][h][cc][kgr][col][8ch]
  bf16_t* bwf  = (bf16_t*)(ws + 67112960);      //  4,718,592 B : W fragments (32x32 layout)
  float*  s    = (float*)(ws + 71831552);       //     32,768 B
  float*  sinv = (float*)(ws + 71864320);       //     32,768 B
  float*  wsq  = (float*)(ws + 71897088);       //  1,048,576 B

  k_style<<<dim3(2, 16), 256, 0, stream>>>(w, lw, lb, s);
  k_wprep<<<dim3(1024), 256, 0, stream>>>(cw, wsq, bwf, (f32x4*)zbuf);
  k_sigma<<<dim3(2, 16), 256, 0, stream>>>(s, wsq, sinv);
  k_xt<<<dim3(4, 64, 16), 256, 0, stream>>>(x, s, xt);
  k_conv<<<dim3(16, 4, 16), 512, 0, stream>>>(ws, bwf, sinv, noise, snz, bias, out);
}

// Round 17
// 295.172 us; speedup vs baseline: 1.1300x; 1.1300x over previous
//
#include <hip/hip_runtime.h>
#include <hip/hip_bf16.h>
#include <stdint.h>

typedef __bf16 bf16_t;
typedef __bf16 bf16x8 __attribute__((ext_vector_type(8)));
typedef short short8 __attribute__((ext_vector_type(8)));
typedef float f32x4 __attribute__((ext_vector_type(4)));

#define RS512  0.044194173824159216f   // 1/sqrt(512)
#define RS4608 0.014731391274719739f   // 1/sqrt(512*9)

// ---------------- K1: style vector  s[b][c] = (w[b,:] . lw[c,:])/sqrt(512) + lb[c]
__global__ void k_style(const float* __restrict__ w, const float* __restrict__ lw,
                        const float* __restrict__ lb, float* __restrict__ s) {
  int b = blockIdx.y;
  int c = blockIdx.x * 256 + threadIdx.x;
  const float4* wr = (const float4*)(w + b * 512);
  const float4* lr = (const float4*)(lw + (size_t)c * 512);
  float acc = 0.f;
#pragma unroll 4
  for (int d = 0; d < 128; ++d) {
    float4 a = wr[d], q = lr[d];
    acc += a.x * q.x + a.y * q.y + a.z * q.z + a.w * q.w;
  }
  s[b * 512 + c] = acc * RS512 + lb[c];
}

// ---------------- K2: wsq + bf16 W fragments (16x16 frag layout, r12/r15-verified); zeros zbuf
// block_idx = (tap*16 + c32)*32 + (o>>4); elem = block_idx*512 + lane*8 + (i&7)
// lane = (o&15) | (((i>>3)&3)<<4). Each 1KB block is one lane-contiguous MFMA A-fragment.
__global__ void k_wprep(const float* __restrict__ cw, float* __restrict__ wsq,
                        bf16_t* __restrict__ bwf, f32x4* __restrict__ zb) {
  if (blockIdx.x == 0) zb[threadIdx.x] = (f32x4)0.f;  // 256*16B = 4KB zeros
  int idx = blockIdx.x * 256 + threadIdx.x;  // o*512 + i
  int o = idx >> 9, i = idx & 511;
  float v[9];
  float ss = 0.f;
#pragma unroll
  for (int t = 0; t < 9; ++t) {
    float x = cw[(size_t)idx * 9 + t] * RS4608;
    v[t] = x;
    ss += x * x;
  }
  wsq[idx] = ss;
  int lane = (o & 15) | (((i >> 3) & 3) << 4);
  int base_blk = (i >> 5) * 32 + (o >> 4);  // c32*32 + fo
#pragma unroll
  for (int t = 0; t < 9; ++t) {
    size_t e = ((size_t)(t * 512 + base_blk) << 9) + lane * 8 + (i & 7);
    bwf[e] = (bf16_t)v[t];
  }
}

// ---------------- K3: sigma_inv[b][o] = rsqrt( sum_i s[b,i]^2 * wsq[o,i] + eps )
__global__ void k_sigma(const float* __restrict__ s, const float* __restrict__ wsq,
                        float* __restrict__ sinv) {
  __shared__ float s2[512];
  int b = blockIdx.y;
  int o = blockIdx.x * 256 + threadIdx.x;
  for (int i = threadIdx.x; i < 512; i += 256) {
    float v = s[b * 512 + i];
    s2[i] = v * v;
  }
  __syncthreads();
  const float4* qr = (const float4*)(wsq + (size_t)o * 512);
  float acc = 0.f;
#pragma unroll 4
  for (int d = 0; d < 128; ++d) {
    float4 q = qr[d];
    acc += q.x * s2[4 * d] + q.y * s2[4 * d + 1] + q.z * s2[4 * d + 2] + q.w * s2[4 * d + 3];
  }
  sinv[b * 512 + o] = rsqrtf(acc + 1e-8f);
}

// ---------------- K4: xt[b][h][cc][kgr][col][8ch] = bf16(x*s)
// Vectorized: float4 global loads (16B/lane), in-register transpose, XOR-swizzled LDS,
// coalesced 1KB/wave global writes.
__global__ void k_xt(const float* __restrict__ x, const float* __restrict__ s,
                     bf16_t* __restrict__ xt) {
  int ic = blockIdx.x, h = blockIdx.y, b = blockIdx.z;
  __shared__ __align__(16) bf16_t tile[8192];  // [16 ig][64 w][8ch], swizzled
  int t = threadIdx.x;
  int q = t & 15;   // w-quad (coalesced global reads)
  int ig = t >> 4;  // 8-ch group 0..15

  float sc[8];
  const float* sp = s + b * 512 + ic * 128 + ig * 8;
#pragma unroll
  for (int k = 0; k < 8; ++k) sc[k] = sp[k];

  float4 m[8];
  const float* xp = x + (((size_t)(b * 512 + ic * 128 + ig * 8)) << 12) + h * 64 + q * 4;
#pragma unroll
  for (int k = 0; k < 8; ++k) m[k] = *(const float4*)(xp + (size_t)k * 4096);

#pragma unroll
  for (int j = 0; j < 4; ++j) {
    bf16x8 v;
#pragma unroll
    for (int k = 0; k < 8; ++k) {
      float e = (j == 0 ? m[k].x : j == 1 ? m[k].y : j == 2 ? m[k].z : m[k].w) * sc[k];
      v[k] = (bf16_t)e;
    }
    uint32_t a = (uint32_t)(ig * 1024 + (q * 4 + j) * 16);
    a ^= ((a >> 6) & 7u) << 4;  // spread transpose-write across 16B slots
    *(bf16x8*)((char*)tile + a) = v;
  }
  __syncthreads();

  int wcol = t & 63, g = t >> 6;
  char* dst = (char*)xt + ((((size_t)b * 64 + h) * 16 + ic * 4) << 12) + g * 1024 + wcol * 16;
#pragma unroll
  for (int j = 0; j < 4; ++j) {
    uint32_t a = (uint32_t)((j * 4 + g) * 1024 + wcol * 16);
    a ^= ((a >> 6) & 7u) << 4;  // same swizzle on read (within-row permutation)
    bf16x8 v = *(bf16x8*)((char*)tile + a);
    *(bf16x8*)(dst + j * 4096) = v;
  }
}

// ---------------- K5: implicit-GEMM conv; r11 skeleton (W-in-LDS, 4 waves/SIMD,
//                  counted-vmcnt per-tap phases) + linear-X addressing (r15-verified)
#define AS1 __attribute__((address_space(1)))
#define AS3 __attribute__((address_space(3)))

__device__ __forceinline__ void gl16(const void* g, void* l) {
  __builtin_amdgcn_global_load_lds((const AS1 void*)g, (AS3 void*)l, 16, 0, 0);
}

#define VMCNT(n) asm volatile("s_waitcnt vmcnt(" #n ")" ::: "memory")
#define BAR __builtin_amdgcn_s_barrier()

// ws layout: zbuf@0 (4KB zeros), xt@4096, bwf@67112960
#define XT0 4096u

// LDS: W[3 slabs][8192B] @0..24575 ; X[2 bufs][6 rows][4 kgr][64 col][16B] @24576..73727
//      + 1KB tail guard (masked edge reads may touch up to 73743)
__global__ __launch_bounds__(512, 4) void k_conv(
    const char* __restrict__ wsb, const bf16_t* __restrict__ bwf,
    const float* __restrict__ sinv, const float* __restrict__ noise,
    const float* __restrict__ snz, const float* __restrict__ bias,
    float* __restrict__ out) {
  __shared__ __align__(16) char lds[74752];

  const int t = threadIdx.x;
  const int rq = blockIdx.x;        // output rows h0..h0+3
  const int OY = blockIdx.y;        // o0 = OY*128
  const int b = blockIdx.z;
  const int h0 = rq * 4;
  const int lane = t & 63;
  const int wv = t >> 6;            // 8 waves
  const int wm = wv & 1;            // o-offset wm*64
  const int wn = wv >> 1;           // output row h0+wn

  f32x4 acc[4][4] = {};

  // ---- X staging: 24 slots of 1KB per buffer; wave wv owns slots wv*3..+2
  uint32_t xsoff[3], xdst[3], xsel[3];
#pragma unroll
  for (int k = 0; k < 3; ++k) {
    int slot = wv * 3 + k, row = slot >> 2, q = slot & 3;
    int gr = h0 - 1 + row;
    int valid = ((unsigned)gr < 64u) ? 1 : 0;
    uint32_t so = valid ? (XT0 + (uint32_t)b * 4194304u + (uint32_t)gr * 65536u +
                           (uint32_t)q * 1024u)
                        : 0u;  // zbuf
    xsoff[k] = __builtin_amdgcn_readfirstlane(so);
    xdst[k] = __builtin_amdgcn_readfirstlane((uint32_t)(24576 + row * 4096 + q * 1024));
    xsel[k] = __builtin_amdgcn_readfirstlane((uint32_t)valid);
  }

  auto stX = [&](int k, uint32_t cxoff, int xb) {
    uint32_t co = xsel[k] ? cxoff : 0u;  // halo slots always read zbuf
    gl16(wsb + xsoff[k] + co + (size_t)(lane * 16), lds + xdst[k] + (uint32_t)(xb * 24576));
  };

  // ---- W staging into LDS (r11 pattern): 1KB/wave per 8KB tap slab
  const char* wgsrc = (const char*)bwf + ((OY * 8 + wv) << 10) + (lane << 4);
  auto stW = [&](uint32_t srcoff, int slab) {
    gl16(wgsrc + srcoff, lds + slab * 8192 + (wv << 10));
  };

  // ---- LDS read bases
  const uint32_t woff = (uint32_t)((wm << 12) + (lane << 4));  // A-frag: +slab*8192+mi*1024
  const uint32_t pXbase =
      (uint32_t)(24576 + wn * 4096 + (lane >> 4) * 1024 + (lane & 15) * 16);
  const bool c0 = (lane & 15) == 0;
  const bool c15 = (lane & 15) == 15;

// one tap: 4 A ds_reads + 4 B ds_reads + 16 MFMA (16x16x32)
#define CTAP(J, XB)                                                            \
  {                                                                            \
    const int ky = (J) / 3, kx = (J) % 3;                                      \
    bf16x8 af[4];                                                              \
    _Pragma("unroll") for (int mi = 0; mi < 4; ++mi)                           \
        af[mi] = *(const bf16x8*)(lds + (uint32_t)(((J) % 3) * 8192) + woff +  \
                                  (uint32_t)(mi * 1024));                      \
    __builtin_amdgcn_s_setprio(1);                                             \
    _Pragma("unroll") for (int col = 0; col < 4; ++col) {                      \
      short8 xv = *(const short8*)(lds + pXbase +                              \
                                   (uint32_t)((XB) * 24576 + ky * 4096 +       \
                                              col * 256 + (kx - 1) * 16));     \
      if (kx == 0 && col == 0) xv = c0 ? (short8)0 : xv;                       \
      if (kx == 2 && col == 3) xv = c15 ? (short8)0 : xv;                      \
      bf16x8 bv = __builtin_bit_cast(bf16x8, xv);                              \
      _Pragma("unroll") for (int mi = 0; mi < 4; ++mi)                         \
          acc[mi][col] = __builtin_amdgcn_mfma_f32_16x16x32_bf16(              \
              af[mi], bv, acc[mi][col], 0, 0, 0);                              \
    }                                                                          \
    __builtin_amdgcn_s_setprio(0);                                             \
  }

// phase (r11 verbatim issue pattern + ledger):
//   steady {3,4,5,4,3,2,2,2,2} ; last chunk {2,2,2,2,2,2,2,1,0}
#define PHASE(CWB, CXB, JC, LAST, XB)                                          \
  {                                                                            \
    if ((JC) + 2 <= 8) stW((CWB) + (uint32_t)((JC) + 2) * 524288u, ((JC) + 2) % 3); \
    else if (!(LAST)) stW((CWB) + 32768u + (uint32_t)((JC) - 7) * 524288u, ((JC) + 2) % 3); \
    if (!(LAST) && (JC) < 3) stX((JC), (CXB), (XB) ^ 1);                       \
    if (LAST) {                                                                \
      if ((JC) <= 6) { VMCNT(2); }                                             \
      else if ((JC) == 7) { VMCNT(1); }                                        \
      else { VMCNT(0); }                                                       \
    } else {                                                                   \
      if ((JC) == 0 || (JC) == 4) { VMCNT(3); }                                \
      else if ((JC) == 1 || (JC) == 3) { VMCNT(4); }                           \
      else if ((JC) == 2) { VMCNT(5); }                                        \
      else { VMCNT(2); }                                                       \
    }                                                                          \
    __builtin_amdgcn_s_barrier();                                              \
    CTAP((JC), (XB));                                                          \
  }

  // prologue: X[0] (halo slots read zbuf) + W taps 0,1 -> slabs 0,1
#pragma unroll
  for (int k = 0; k < 3; ++k) stX(k, 0u, 0);
  stW(0u, 0);
  stW(524288u, 1);
  VMCNT(0); BAR;

  uint32_t cwb = 0, cxb = 4096;
#pragma unroll 1
  for (int ci = 0; ci < 7; ++ci) {
#pragma unroll
    for (int jc = 0; jc < 9; ++jc) PHASE(cwb, cxb, jc, 0, 0);
    cwb += 32768u; cxb += 4096u;
#pragma unroll
    for (int jc = 0; jc < 9; ++jc) PHASE(cwb, cxb, jc, 0, 1);
    cwb += 32768u; cxb += 4096u;
  }
#pragma unroll
  for (int jc = 0; jc < 9; ++jc) PHASE(cwb, cxb, jc, 0, 0);  // chunk 14 (stages X[15])
  cwb += 32768u;
#pragma unroll
  for (int jc = 0; jc < 9; ++jc) PHASE(cwb, 0u, jc, 1, 1);   // chunk 15 (LAST)

  // epilogue: demod scale + noise + bias + leaky relu (one output row per wave)
  const float* sb = sinv + b * 512;
  const int og = OY * 128 + wm * 64 + ((lane >> 4) << 2);
  const int colb = lane & 15;
  const int prow = h0 + wn;
  float nzv[4];
#pragma unroll
  for (int col = 0; col < 4; ++col)
    nzv[col] = noise[(size_t)b * 4096 + prow * 64 + col * 16 + colb];
#pragma unroll
  for (int mi = 0; mi < 4; ++mi) {
#pragma unroll
    for (int r = 0; r < 4; ++r) {
      int o = og + mi * 16 + r;
      float sv = sb[o];
      float nw = snz[o];
      float bv = bias[o];
      float* orow = out + (((size_t)b * 512 + o) * 64 + prow) * 64;
#pragma unroll
      for (int col = 0; col < 4; ++col) {
        float v = acc[mi][col][r] * sv + nw * nzv[col] + bv;
        orow[col * 16 + colb] = v > 0.f ? v : 0.2f * v;
      }
    }
  }
}

extern "C" void kernel_launch(void* const* d_in, const int* in_sizes, int n_in,
                              void* d_out, int out_size, void* d_ws, size_t ws_size,
                              hipStream_t stream) {
  const float* x     = (const float*)d_in[0];
  const float* w     = (const float*)d_in[1];
  const float* noise = (const float*)d_in[2];
  const float* lw    = (const float*)d_in[3];
  const float* lb    = (const float*)d_in[4];
  const float* cw    = (const float*)d_in[5];
  const float* snz   = (const float*)d_in[6];
  const float* bias  = (const float*)d_in[7];
  float* out = (float*)d_out;

  char* ws = (char*)d_ws;
  char*   zbuf = ws;                            //      4,096 B zeros
  bf16_t* xt   = (bf16_t*)(ws + 4096);          // 67,108,864 B : [b][h][cc][kgr][col][8ch]
  bf16_t* bwf  = (bf16_t*)(ws + 67112960);      //  4,718,592 B : W fragments (16x16 layout)
  float*  s    = (float*)(ws + 71831552);       //     32,768 B
  float*  sinv = (float*)(ws + 71864320);       //     32,768 B
  float*  wsq  = (float*)(ws + 71897088);       //  1,048,576 B

  k_style<<<dim3(2, 16), 256, 0, stream>>>(w, lw, lb, s);
  k_wprep<<<dim3(1024), 256, 0, stream>>>(cw, wsq, bwf, (f32x4*)zbuf);
  k_sigma<<<dim3(2, 16), 256, 0, stream>>>(s, wsq, sinv);
  k_xt<<<dim3(4, 64, 16), 256, 0, stream>>>(x, s, xt);
  k_conv<<<dim3(16, 4, 16), 512, 0, stream>>>(ws, bwf, sinv, noise, snz, bias, out);
}